// Round 1
// baseline (14891.893 us; speedup 1.0000x reference)
//
#include <hip/hip_runtime.h>
#include <math.h>

#define BB 32
#define TT 2048
#define HH 128

// LDS-only barrier: waits LDS ops (lgkmcnt), leaves global loads/stores in
// flight across the barrier.
#define LDS_BARRIER() asm volatile("s_waitcnt lgkmcnt(0)\n\ts_barrier" ::: "memory")

// DPP quad_perm helper: returns v[quad_perm] within each 4-lane quad.
// CTRL = p0 | p1<<2 | p2<<4 | p3<<6.  xor1 = 0xB1, xor2 = 0x4E, bcast q = q*0x55.
#define QPERM_F(v, CTRL)                                                      \
  __int_as_float(__builtin_amdgcn_update_dpp(                                 \
      0, __float_as_int(v), (CTRL), 0xF, 0xF, true))

// ---------------------------------------------------------------------------
// proj kernel: out[r, :] = emb[tokens[r]] @ W + bias   (layer-0 input proj)
// ---------------------------------------------------------------------------
template <bool GATHER>
__global__ __launch_bounds__(256) void proj_kernel(
    const float* __restrict__ src, const int* __restrict__ tokens,
    const float* __restrict__ W, const float* __restrict__ bias,
    float* __restrict__ out) {
  const int tid = threadIdx.x;
  const int jj = tid & 31;
  const int rr = tid >> 5;
  const int base = blockIdx.x * 64;

  __shared__ __align__(16) float srow[64][HH];
  __shared__ int stok[64];

  if (GATHER) {
    if (tid < 64) stok[tid] = tokens[base + tid];
    __syncthreads();
  }

#pragma unroll
  for (int i = 0; i < 8; ++i) {
    int idx = tid + i * 256;
    int row = idx >> 5;
    int c4 = idx & 31;
    const float* s = GATHER ? (src + (size_t)stok[row] * HH)
                            : (src + (size_t)(base + row) * HH);
    *(float4*)&srow[row][c4 * 4] = *(const float4*)&s[c4 * 4];
  }
  __syncthreads();

  float4 b4 = *(const float4*)&bias[jj * 4];
  float4 acc[8];
#pragma unroll
  for (int i = 0; i < 8; ++i) acc[i] = b4;

  for (int k = 0; k < HH; ++k) {
    float4 w4 = *(const float4*)&W[k * HH + jj * 4];
#pragma unroll
    for (int i = 0; i < 8; ++i) {
      float e = srow[rr * 8 + i][k];
      acc[i].x += e * w4.x;
      acc[i].y += e * w4.y;
      acc[i].z += e * w4.z;
      acc[i].w += e * w4.w;
    }
  }

#pragma unroll
  for (int i = 0; i < 8; ++i) {
    int row = base + rr * 8 + i;
    *(float4*)&out[(size_t)row * HH + jj * 4] = acc[i];
  }
}

// ---------------------------------------------------------------------------
// fused rnn kernel: BOTH layers, wavefront-pipelined (layer 1 lags 1 step).
// 1024 threads/block, one block per batch.
//   group L0 (tid < 512):  h0[s] = tanh(xp0[s] + h0[s-1] @ Wh0)
//   group L1 (tid >= 512): h1[s-1] = tanh(h0[s-1] @ Wx1 + b1 + h1[s-2] @ Wh1)
// Thread (j = t512>>2, p = t512&3) holds 32 weights per matvec (k = 16i+4p+r),
// quad-split dot + DPP quad-reduce, identical to the proven v3 structure.
// h0/h1 published via double-buffered LDS; ONE lgkm-barrier per superstep.
// 2049 serialized supersteps instead of 4096, and layer-0 output never
// touches global memory (no ys0 write, no proj1 pass, no xp1 read).
// ---------------------------------------------------------------------------
__global__ __launch_bounds__(1024) void rnn_fused_kernel(
    const float* __restrict__ xp0, float* __restrict__ out,
    const float* __restrict__ Wh0, const float* __restrict__ Wx1,
    const float* __restrict__ Wh1, const float* __restrict__ b1,
    const int* __restrict__ tokens) {
  const int b = blockIdx.x;
  const int tid = threadIdx.x;
  const bool g1 = tid >= 512;  // wave-uniform group flag
  const int t512 = tid & 511;
  const int j = t512 >> 2;  // output column 0..127
  const int p = t512 & 3;   // k-split 0..3
  const int lane = tid & 63;

  // Weights: w = Wh0 (L0) or Wx1 (L1); w2 = Wh1 (L1 only).
  // w[c] <-> k = 16*(c>>2) + 4*p + (c&3)
  float w[32];
  float w2[32];
#pragma unroll
  for (int c = 0; c < 32; ++c) {
    int k = 16 * (c >> 2) + 4 * p + (c & 3);
    if (!g1) {
      w[c] = Wh0[k * HH + j];
      w2[c] = 0.0f;
    } else {
      w[c] = Wx1[k * HH + j];
      w2[c] = Wh1[k * HH + j];
    }
  }
  const float bias = g1 ? b1[j] : 0.0f;

  // Mask bitmask: lane l holds bits for t in [32l, 32l+32). Replicated per wave.
  const int* tok = tokens + b * TT;
  unsigned bits = 0;
#pragma unroll
  for (int i = 0; i < 8; ++i) {
    int4 tk = *(const int4*)&tok[lane * 32 + i * 4];
    bits |= (unsigned)(tk.x != 0) << (i * 4 + 0);
    bits |= (unsigned)(tk.y != 0) << (i * 4 + 1);
    bits |= (unsigned)(tk.z != 0) << (i * 4 + 2);
    bits |= (unsigned)(tk.w != 0) << (i * 4 + 3);
  }

  __shared__ __align__(16) float h0s[2][HH];
  __shared__ __align__(16) float h1s[2][HH];
  if (tid < HH) {
    h0s[0][tid] = 0.0f;  // h0[-1]
    h1s[0][tid] = 0.0f;
    h1s[1][tid] = 0.0f;  // h1[-1]
  }

  const float* xp = xp0 + (size_t)b * TT * HH;
  float* outp = out + (size_t)b * TT * HH;

  float h = 0.0f;  // carry state: h0 for L0 threads, h1 for L1 threads
  float xcur = 0.0f;
  if (!g1) xcur = xp[(size_t)p * HH + j];  // lane p holds x for step t0+p
  LDS_BARRIER();

#define TANH_MASK(S, TM, HREG)                                                \
  {                                                                           \
    unsigned word =                                                           \
        (unsigned)__builtin_amdgcn_readlane((int)bits, (TM) >> 5);            \
    int m = (word >> ((TM) & 31)) & 1;                                        \
    float ax = fabsf(S);                                                      \
    float e = __expf(-2.0f * ax);                                             \
    float th = (1.0f - e) * __builtin_amdgcn_rcpf(1.0f + e);                  \
    th = copysignf(th, (S));                                                  \
    HREG = m ? th : HREG;                                                     \
  }

#define RNN_STEP(Q)                                                           \
  {                                                                           \
    const int t = t0 + (Q); /* superstep index == L0 step index */            \
    const int pr = t & 1;                                                     \
    const int pw = (t + 1) & 1;                                               \
    if (!g1) {                                                                \
      const float* hb = h0s[pr];                                              \
      float a0 = 0.f, a1 = 0.f, a2 = 0.f, a3 = 0.f;                           \
      _Pragma("unroll") for (int i = 0; i < 8; ++i) {                         \
        float4 hv = *(const float4*)&hb[16 * i + 4 * p];                      \
        a0 += hv.x * w[4 * i + 0];                                            \
        a1 += hv.y * w[4 * i + 1];                                            \
        a2 += hv.z * w[4 * i + 2];                                            \
        a3 += hv.w * w[4 * i + 3];                                            \
      }                                                                       \
      float acc = (a0 + a1) + (a2 + a3);                                      \
      acc += QPERM_F(acc, 0xB1); /* xor 1 */                                  \
      acc += QPERM_F(acc, 0x4E); /* xor 2 */                                  \
      float x = QPERM_F(xcur, (Q)*0x55); /* quad-broadcast lane Q */          \
      float s = acc + x;                                                      \
      TANH_MASK(s, t, h)                                                      \
      if (p == 0) h0s[pw][j] = h; /* publish h0[t] */                         \
    } else {                                                                  \
      const int t1 = t - 1; /* L1 step index */                               \
      if (t1 >= 0) {                                                          \
        const float* hb0 = h0s[pr]; /* h0[t1] */                              \
        const float* hb1 = h1s[pr]; /* h1[t1-1] */                            \
        float a0 = 0.f, a1 = 0.f, a2 = 0.f, a3 = 0.f;                         \
        float c0 = 0.f, c1 = 0.f, c2 = 0.f, c3 = 0.f;                         \
        _Pragma("unroll") for (int i = 0; i < 8; ++i) {                       \
          float4 hv = *(const float4*)&hb0[16 * i + 4 * p];                   \
          float4 gv = *(const float4*)&hb1[16 * i + 4 * p];                   \
          a0 += hv.x * w[4 * i + 0];                                          \
          a1 += hv.y * w[4 * i + 1];                                          \
          a2 += hv.z * w[4 * i + 2];                                          \
          a3 += hv.w * w[4 * i + 3];                                          \
          c0 += gv.x * w2[4 * i + 0];                                         \
          c1 += gv.y * w2[4 * i + 1];                                         \
          c2 += gv.z * w2[4 * i + 2];                                         \
          c3 += gv.w * w2[4 * i + 3];                                         \
        }                                                                     \
        float acc = ((a0 + a1) + (a2 + a3)) + ((c0 + c1) + (c2 + c3));        \
        acc += QPERM_F(acc, 0xB1); /* xor 1 */                                \
        acc += QPERM_F(acc, 0x4E); /* xor 2 */                                \
        float s = acc + bias;                                                 \
        TANH_MASK(s, t1, h)                                                   \
        if (p == 0) {                                                         \
          h1s[pw][j] = h;                       /* publish h1[t1] */          \
          outp[(size_t)t1 * HH + j] = h;        /* final output */            \
        }                                                                     \
      }                                                                       \
    }                                                                         \
    LDS_BARRIER();                                                            \
  }

  for (int t0 = 0; t0 < TT; t0 += 4) {
    float xnext = 0.0f;
    if (!g1 && t0 + 4 < TT) xnext = xp[(size_t)(t0 + 4 + p) * HH + j];
    RNN_STEP(0)
    RNN_STEP(1)
    RNN_STEP(2)
    RNN_STEP(3)
    xcur = xnext;
  }
#undef RNN_STEP

  // Tail superstep s = TT: L1 computes h1[TT-1]. h0[TT-1] is in h0s[TT&1==0],
  // h1[TT-2] in h1s[0] (both written during superstep TT-1, barrier passed).
  if (g1) {
    const int t1 = TT - 1;
    const float* hb0 = h0s[0];
    const float* hb1 = h1s[0];
    float a0 = 0.f, a1 = 0.f, a2 = 0.f, a3 = 0.f;
    float c0 = 0.f, c1 = 0.f, c2 = 0.f, c3 = 0.f;
#pragma unroll
    for (int i = 0; i < 8; ++i) {
      float4 hv = *(const float4*)&hb0[16 * i + 4 * p];
      float4 gv = *(const float4*)&hb1[16 * i + 4 * p];
      a0 += hv.x * w[4 * i + 0];
      a1 += hv.y * w[4 * i + 1];
      a2 += hv.z * w[4 * i + 2];
      a3 += hv.w * w[4 * i + 3];
      c0 += gv.x * w2[4 * i + 0];
      c1 += gv.y * w2[4 * i + 1];
      c2 += gv.z * w2[4 * i + 2];
      c3 += gv.w * w2[4 * i + 3];
    }
    float acc = ((a0 + a1) + (a2 + a3)) + ((c0 + c1) + (c2 + c3));
    acc += QPERM_F(acc, 0xB1);
    acc += QPERM_F(acc, 0x4E);
    float s = acc + bias;
    TANH_MASK(s, t1, h)
    if (p == 0) outp[(size_t)t1 * HH + j] = h;
  }
#undef TANH_MASK
}

extern "C" void kernel_launch(void* const* d_in, const int* in_sizes, int n_in,
                              void* d_out, int out_size, void* d_ws,
                              size_t ws_size, hipStream_t stream) {
  const int* tokens = (const int*)d_in[0];
  const float* emb = (const float*)d_in[1];
  const float* Wx0 = (const float*)d_in[2];
  const float* Wh0 = (const float*)d_in[3];
  const float* b0 = (const float*)d_in[4];
  const float* Wx1 = (const float*)d_in[5];
  const float* Wh1 = (const float*)d_in[6];
  const float* b1 = (const float*)d_in[7];
  float* out = (float*)d_out;
  float* ws = (float*)d_ws;  // 32 MB: xp0

  const int rows = BB * TT;           // 65536
  const int proj_blocks = rows / 64;  // 1024

  proj_kernel<true><<<proj_blocks, 256, 0, stream>>>(emb, tokens, Wx0, b0, ws);
  rnn_fused_kernel<<<BB, 1024, 0, stream>>>(ws, out, Wh0, Wx1, Wh1, b1,
                                            tokens);
}

// Round 2
// 5861.814 us; speedup vs baseline: 2.5405x; 2.5405x over previous
//
#include <hip/hip_runtime.h>
#include <math.h>

#define BB 32
#define TT 2048
#define HH 128

// LDS-only barrier: waits LDS ops (lgkmcnt), leaves global loads/stores in
// flight across the barrier.
#define LDS_BARRIER() asm volatile("s_waitcnt lgkmcnt(0)\n\ts_barrier" ::: "memory")

// DPP quad_perm helper: returns v[quad_perm] within each 4-lane quad.
// CTRL = p0 | p1<<2 | p2<<4 | p3<<6.  xor1 = 0xB1, xor2 = 0x4E, bcast q = q*0x55.
#define QPERM_F(v, CTRL)                                                      \
  __int_as_float(__builtin_amdgcn_update_dpp(                                 \
      0, __float_as_int(v), (CTRL), 0xF, 0xF, true))

// ---------------------------------------------------------------------------
// proj kernel: out[r, :] = emb[tokens[r]] @ W + bias   (layer-0 input proj)
// ---------------------------------------------------------------------------
template <bool GATHER>
__global__ __launch_bounds__(256) void proj_kernel(
    const float* __restrict__ src, const int* __restrict__ tokens,
    const float* __restrict__ W, const float* __restrict__ bias,
    float* __restrict__ out) {
  const int tid = threadIdx.x;
  const int jj = tid & 31;
  const int rr = tid >> 5;
  const int base = blockIdx.x * 64;

  __shared__ __align__(16) float srow[64][HH];
  __shared__ int stok[64];

  if (GATHER) {
    if (tid < 64) stok[tid] = tokens[base + tid];
    __syncthreads();
  }

#pragma unroll
  for (int i = 0; i < 8; ++i) {
    int idx = tid + i * 256;
    int row = idx >> 5;
    int c4 = idx & 31;
    const float* s = GATHER ? (src + (size_t)stok[row] * HH)
                            : (src + (size_t)(base + row) * HH);
    *(float4*)&srow[row][c4 * 4] = *(const float4*)&s[c4 * 4];
  }
  __syncthreads();

  float4 b4 = *(const float4*)&bias[jj * 4];
  float4 acc[8];
#pragma unroll
  for (int i = 0; i < 8; ++i) acc[i] = b4;

  for (int k = 0; k < HH; ++k) {
    float4 w4 = *(const float4*)&W[k * HH + jj * 4];
#pragma unroll
    for (int i = 0; i < 8; ++i) {
      float e = srow[rr * 8 + i][k];
      acc[i].x += e * w4.x;
      acc[i].y += e * w4.y;
      acc[i].z += e * w4.z;
      acc[i].w += e * w4.w;
    }
  }

#pragma unroll
  for (int i = 0; i < 8; ++i) {
    int row = base + rr * 8 + i;
    *(float4*)&out[(size_t)row * HH + jj * 4] = acc[i];
  }
}

// ---------------------------------------------------------------------------
// fused rnn kernel: BOTH layers, wavefront-pipelined (layer 1 lags 1 step).
// 1024 threads/block, one block per batch.
//   group L0 (tid < 512):  h0[s] = tanh(xp0[s] + h0[s-1] @ Wh0)
//   group L1 (tid >= 512): h1[s-1] = tanh(h0[s-1] @ Wx1 + b1 + h1[s-2] @ Wh1)
// Thread (j = t512>>2, p = t512&3) holds 32 weights per matvec (k = 16i+4p+r),
// quad-split dot + DPP quad-reduce.
//
// __launch_bounds__(1024, 4): 4 waves/EU == exactly one 16-wave block/CU,
// raising the VGPR cap to 128. Round-1 failure: default heuristic capped at
// 64 VGPRs -> w[]/w2[] spilled to scratch -> 295 MB of per-step spill traffic
// (WRITE_SIZE 328 MB vs 33 MB output), VALUBusy 1.3%, 23x/step slowdown.
// ---------------------------------------------------------------------------
__global__ __launch_bounds__(1024, 4) void rnn_fused_kernel(
    const float* __restrict__ xp0, float* __restrict__ out,
    const float* __restrict__ Wh0, const float* __restrict__ Wx1,
    const float* __restrict__ Wh1, const float* __restrict__ b1,
    const int* __restrict__ tokens) {
  const int b = blockIdx.x;
  const int tid = threadIdx.x;
  const bool g1 = tid >= 512;  // wave-uniform group flag
  const int t512 = tid & 511;
  const int j = t512 >> 2;  // output column 0..127
  const int p = t512 & 3;   // k-split 0..3
  const int lane = tid & 63;

  // Weights: w = Wh0 (L0) or Wx1 (L1); w2 = Wh1 (L1 only, uninit for L0).
  // w[c] <-> k = 16*(c>>2) + 4*p + (c&3)
  float w[32];
  float w2[32];
  float bias = 0.0f;
  if (!g1) {
#pragma unroll
    for (int c = 0; c < 32; ++c) {
      int k = 16 * (c >> 2) + 4 * p + (c & 3);
      w[c] = Wh0[k * HH + j];
    }
  } else {
#pragma unroll
    for (int c = 0; c < 32; ++c) {
      int k = 16 * (c >> 2) + 4 * p + (c & 3);
      w[c] = Wx1[k * HH + j];
      w2[c] = Wh1[k * HH + j];
    }
    bias = b1[j];
  }

  // Mask bitmask: lane l holds bits for t in [32l, 32l+32). Replicated per wave.
  const int* tok = tokens + b * TT;
  unsigned bits = 0;
#pragma unroll
  for (int i = 0; i < 8; ++i) {
    int4 tk = *(const int4*)&tok[lane * 32 + i * 4];
    bits |= (unsigned)(tk.x != 0) << (i * 4 + 0);
    bits |= (unsigned)(tk.y != 0) << (i * 4 + 1);
    bits |= (unsigned)(tk.z != 0) << (i * 4 + 2);
    bits |= (unsigned)(tk.w != 0) << (i * 4 + 3);
  }

  __shared__ __align__(16) float h0s[2][HH];
  __shared__ __align__(16) float h1s[2][HH];
  if (tid < HH) {
    h0s[0][tid] = 0.0f;  // h0[-1]
    h1s[0][tid] = 0.0f;
    h1s[1][tid] = 0.0f;  // h1[-1]
  }

  const float* xp = xp0 + (size_t)b * TT * HH;
  float* outp = out + (size_t)b * TT * HH;

  float h = 0.0f;  // carry state: h0 for L0 threads, h1 for L1 threads
  float xcur = 0.0f;
  if (!g1) xcur = xp[(size_t)p * HH + j];  // lane p holds x for step t0+p
  LDS_BARRIER();

#define TANH_MASK(S, TM, HREG)                                                \
  {                                                                           \
    unsigned word =                                                           \
        (unsigned)__builtin_amdgcn_readlane((int)bits, (TM) >> 5);            \
    int m = (word >> ((TM) & 31)) & 1;                                        \
    float ax = fabsf(S);                                                      \
    float e = __expf(-2.0f * ax);                                             \
    float th = (1.0f - e) * __builtin_amdgcn_rcpf(1.0f + e);                  \
    th = copysignf(th, (S));                                                  \
    HREG = m ? th : HREG;                                                     \
  }

#define RNN_STEP(Q)                                                           \
  {                                                                           \
    const int t = t0 + (Q); /* superstep index == L0 step index */            \
    const int pr = t & 1;                                                     \
    const int pw = (t + 1) & 1;                                               \
    if (!g1) {                                                                \
      const float* hb = h0s[pr];                                              \
      float a0 = 0.f, a1 = 0.f, a2 = 0.f, a3 = 0.f;                           \
      _Pragma("unroll") for (int i = 0; i < 8; ++i) {                         \
        float4 hv = *(const float4*)&hb[16 * i + 4 * p];                      \
        a0 += hv.x * w[4 * i + 0];                                            \
        a1 += hv.y * w[4 * i + 1];                                            \
        a2 += hv.z * w[4 * i + 2];                                            \
        a3 += hv.w * w[4 * i + 3];                                            \
      }                                                                       \
      float acc = (a0 + a1) + (a2 + a3);                                      \
      acc += QPERM_F(acc, 0xB1); /* xor 1 */                                  \
      acc += QPERM_F(acc, 0x4E); /* xor 2 */                                  \
      float x = QPERM_F(xcur, (Q)*0x55); /* quad-broadcast lane Q */          \
      float s = acc + x;                                                      \
      TANH_MASK(s, t, h)                                                      \
      if (p == 0) h0s[pw][j] = h; /* publish h0[t] */                         \
    } else {                                                                  \
      const int t1 = t - 1; /* L1 step index */                               \
      if (t1 >= 0) {                                                          \
        const float* hb0 = h0s[pr]; /* h0[t1] */                              \
        const float* hb1 = h1s[pr]; /* h1[t1-1] */                            \
        float a0 = 0.f, a1 = 0.f, a2 = 0.f, a3 = 0.f;                         \
        float c0 = 0.f, c1 = 0.f, c2 = 0.f, c3 = 0.f;                         \
        _Pragma("unroll") for (int i = 0; i < 8; ++i) {                       \
          float4 hv = *(const float4*)&hb0[16 * i + 4 * p];                   \
          float4 gv = *(const float4*)&hb1[16 * i + 4 * p];                   \
          a0 += hv.x * w[4 * i + 0];                                          \
          a1 += hv.y * w[4 * i + 1];                                          \
          a2 += hv.z * w[4 * i + 2];                                          \
          a3 += hv.w * w[4 * i + 3];                                          \
          c0 += gv.x * w2[4 * i + 0];                                         \
          c1 += gv.y * w2[4 * i + 1];                                         \
          c2 += gv.z * w2[4 * i + 2];                                         \
          c3 += gv.w * w2[4 * i + 3];                                         \
        }                                                                     \
        float acc = ((a0 + a1) + (a2 + a3)) + ((c0 + c1) + (c2 + c3));        \
        acc += QPERM_F(acc, 0xB1); /* xor 1 */                                \
        acc += QPERM_F(acc, 0x4E); /* xor 2 */                                \
        float s = acc + bias;                                                 \
        TANH_MASK(s, t1, h)                                                   \
        if (p == 0) {                                                         \
          h1s[pw][j] = h;                /* publish h1[t1] */                 \
          outp[(size_t)t1 * HH + j] = h; /* final output */                   \
        }                                                                     \
      }                                                                       \
    }                                                                         \
    LDS_BARRIER();                                                            \
  }

  for (int t0 = 0; t0 < TT; t0 += 4) {
    float xnext = 0.0f;
    if (!g1 && t0 + 4 < TT) xnext = xp[(size_t)(t0 + 4 + p) * HH + j];
    RNN_STEP(0)
    RNN_STEP(1)
    RNN_STEP(2)
    RNN_STEP(3)
    xcur = xnext;
  }
#undef RNN_STEP

  // Tail superstep s = TT: L1 computes h1[TT-1]. h0[TT-1] is in h0s[TT&1==0],
  // h1[TT-2] in h1s[0] (both written during superstep TT-1, barrier passed).
  if (g1) {
    const int t1 = TT - 1;
    const float* hb0 = h0s[0];
    const float* hb1 = h1s[0];
    float a0 = 0.f, a1 = 0.f, a2 = 0.f, a3 = 0.f;
    float c0 = 0.f, c1 = 0.f, c2 = 0.f, c3 = 0.f;
#pragma unroll
    for (int i = 0; i < 8; ++i) {
      float4 hv = *(const float4*)&hb0[16 * i + 4 * p];
      float4 gv = *(const float4*)&hb1[16 * i + 4 * p];
      a0 += hv.x * w[4 * i + 0];
      a1 += hv.y * w[4 * i + 1];
      a2 += hv.z * w[4 * i + 2];
      a3 += hv.w * w[4 * i + 3];
      c0 += gv.x * w2[4 * i + 0];
      c1 += gv.y * w2[4 * i + 1];
      c2 += gv.z * w2[4 * i + 2];
      c3 += gv.w * w2[4 * i + 3];
    }
    float acc = ((a0 + a1) + (a2 + a3)) + ((c0 + c1) + (c2 + c3));
    acc += QPERM_F(acc, 0xB1);
    acc += QPERM_F(acc, 0x4E);
    float s = acc + bias;
    TANH_MASK(s, t1, h)
    if (p == 0) outp[(size_t)t1 * HH + j] = h;
  }
#undef TANH_MASK
}

extern "C" void kernel_launch(void* const* d_in, const int* in_sizes, int n_in,
                              void* d_out, int out_size, void* d_ws,
                              size_t ws_size, hipStream_t stream) {
  const int* tokens = (const int*)d_in[0];
  const float* emb = (const float*)d_in[1];
  const float* Wx0 = (const float*)d_in[2];
  const float* Wh0 = (const float*)d_in[3];
  const float* b0 = (const float*)d_in[4];
  const float* Wx1 = (const float*)d_in[5];
  const float* Wh1 = (const float*)d_in[6];
  const float* b1 = (const float*)d_in[7];
  float* out = (float*)d_out;
  float* ws = (float*)d_ws;  // 32 MB: xp0

  const int rows = BB * TT;           // 65536
  const int proj_blocks = rows / 64;  // 1024

  proj_kernel<true><<<proj_blocks, 256, 0, stream>>>(emb, tokens, Wx0, b0, ws);
  rnn_fused_kernel<<<BB, 1024, 0, stream>>>(ws, out, Wh0, Wx1, Wh1, b1,
                                            tokens);
}

// Round 4
// 1556.764 us; speedup vs baseline: 9.5659x; 3.7654x over previous
//
#include <hip/hip_runtime.h>
#include <math.h>

#define BB 32
#define TT 2048
#define HH 128

typedef float f32x2 __attribute__((ext_vector_type(2)));

// LDS-only barrier: waits LDS ops (lgkmcnt), leaves global loads/stores in
// flight across the barrier.
#define LDS_BARRIER() asm volatile("s_waitcnt lgkmcnt(0)\n\ts_barrier" ::: "memory")

// DPP quad_perm helper: returns v[quad_perm] within each 4-lane quad.
#define QPERM_F(v, CTRL)                                                      \
  __int_as_float(__builtin_amdgcn_update_dpp(                                 \
      0, __float_as_int(v), (CTRL), 0xF, 0xF, true))

// Butterfly sum across the 8 k-split lanes (lane bits [2:0]).
// xor1/xor2 are DPP quad perms; xor4 via ds_swizzle BitMode (xor_mask=4).
__device__ __forceinline__ float red8(float a) {
  a += QPERM_F(a, 0xB1);  // xor lane bit 0
  a += QPERM_F(a, 0x4E);  // xor lane bit 1
  a += __int_as_float(
      __builtin_amdgcn_ds_swizzle(__float_as_int(a), 0x101F));  // xor bit 2
  return a;
}

__device__ __forceinline__ float tanh_fast(float s) {
  float ax = fabsf(s);
  float e = __expf(-2.0f * ax);
  float th = (1.0f - e) * __builtin_amdgcn_rcpf(1.0f + e);
  return copysignf(th, s);
}

// ---------------------------------------------------------------------------
// proj kernel: out[r, :] = emb[tokens[r]] @ Wx0 + b0   (layer-0 input proj)
// ---------------------------------------------------------------------------
template <bool GATHER>
__global__ __launch_bounds__(256) void proj_kernel(
    const float* __restrict__ src, const int* __restrict__ tokens,
    const float* __restrict__ W, const float* __restrict__ bias,
    float* __restrict__ out) {
  const int tid = threadIdx.x;
  const int jj = tid & 31;
  const int rr = tid >> 5;
  const int base = blockIdx.x * 64;

  __shared__ __align__(16) float srow[64][HH];
  __shared__ int stok[64];

  if (GATHER) {
    if (tid < 64) stok[tid] = tokens[base + tid];
    __syncthreads();
  }

#pragma unroll
  for (int i = 0; i < 8; ++i) {
    int idx = tid + i * 256;
    int row = idx >> 5;
    int c4 = idx & 31;
    const float* s = GATHER ? (src + (size_t)stok[row] * HH)
                            : (src + (size_t)(base + row) * HH);
    *(float4*)&srow[row][c4 * 4] = *(const float4*)&s[c4 * 4];
  }
  __syncthreads();

  float4 b4 = *(const float4*)&bias[jj * 4];
  float4 acc[8];
#pragma unroll
  for (int i = 0; i < 8; ++i) acc[i] = b4;

  for (int k = 0; k < HH; ++k) {
    float4 w4 = *(const float4*)&W[k * HH + jj * 4];
#pragma unroll
    for (int i = 0; i < 8; ++i) {
      float e = srow[rr * 8 + i][k];
      acc[i].x += e * w4.x;
      acc[i].y += e * w4.y;
      acc[i].z += e * w4.z;
      acc[i].w += e * w4.w;
    }
  }

#pragma unroll
  for (int i = 0; i < 8; ++i) {
    int row = base + rr * 8 + i;
    *(float4*)&out[(size_t)row * HH + jj * 4] = acc[i];
  }
}

// ---------------------------------------------------------------------------
// fused rnn kernel v5 (R3 = identical resubmission; R3 bench was an infra
// failure "container failed twice" — no counters, no pass/fail verdict;
// kernel audited: uniform barriers, no OOB, fixed trip counts -> no hang).
//
// Both layers, wavefront-pipelined, C=4 column reuse.
// LDS-return-BW model: v3's 745 cy/step == 512thr*128B / 85 B/cy. Volume is
// the binding resource; one h-float in-register must feed C columns.
// 256 threads (4 waves), thread (jgg = cols 4jgg..+3, p = k-chunk [16p,16p+16)):
//   - holds Wh0/Wx1/Wh1 rows 16p..16p+15 x cols 4jgg..+3 = 192 weight VGPRs
//   - per superstep t: read 16 h0[t-1] floats (feed BOTH Wh0-dot and Wx1-dot)
//     + 16 h1[t-2] floats = 128 B/thread -> 32 KB/block/step (1/4 of v3)
//   - 192 FMAs as f32x2 (v_pk_fma), reduce over 8 p-lanes (2 DPP + 1 swizzle)
//   - L0: h0[t] = tanh(x[t] + h0[t-1]@Wh0);  L1: h1[t-1] = tanh(h0[t-1]@Wx1
//     + h1[t-2]@Wh1 + b1).  p==0 lanes publish to LDS + store out.
// h buffers: chunk p at 80-byte stride -> 8 chunk addrs cover all 32 banks
// distinctly -> conflict-free broadcast reads.
//
// __launch_bounds__(256, 1): R1/R2 evidence says hipcc reads arg2 as min
// BLOCKS/CU (CUDA semantics): (1024,4) clamped to 2 blocks -> 64-VGPR cap ->
// weight spills (R1: 295 MB HBM spill traffic; R2: L2-served scratch reloads,
// 5.8 ms). (256,1) -> 4 waves/CU -> 512-VGPR cap under either interpretation.
// ---------------------------------------------------------------------------
__global__ __launch_bounds__(256, 1) void rnn_fused_kernel(
    const float* __restrict__ xp0, float* __restrict__ out,
    const float* __restrict__ Wh0, const float* __restrict__ Wx1,
    const float* __restrict__ Wh1, const float* __restrict__ b1,
    const int* __restrict__ tokens) {
  const int b = blockIdx.x;
  const int tid = threadIdx.x;
  const int lane = tid & 63;
  const int p = lane & 7;                           // k-split 0..7
  const int jgg = (lane >> 3) + ((tid >> 6) << 3);  // col-group 0..31
  const int col = 4 * jgg;

  // weights: rows 16p..16p+15, cols col..col+3 of Wh0 / Wx1 / Wh1
  f32x2 w0a[16], w0b[16], wxa[16], wxb[16], wha[16], whb[16];
#pragma unroll
  for (int i = 0; i < 16; ++i) {
    int row = 16 * p + i;
    w0a[i] = *(const f32x2*)&Wh0[row * HH + col];
    w0b[i] = *(const f32x2*)&Wh0[row * HH + col + 2];
    wxa[i] = *(const f32x2*)&Wx1[row * HH + col];
    wxb[i] = *(const f32x2*)&Wx1[row * HH + col + 2];
    wha[i] = *(const f32x2*)&Wh1[row * HH + col];
    whb[i] = *(const f32x2*)&Wh1[row * HH + col + 2];
  }
  const float4 bias = *(const float4*)&b1[col];

  // mask bitmask: lane l holds bits for t in [32l, 32l+32); replicated/wave.
  const int* tok = tokens + b * TT;
  unsigned bits = 0;
#pragma unroll
  for (int i = 0; i < 8; ++i) {
    int4 tk = *(const int4*)&tok[lane * 32 + i * 4];
    bits |= (unsigned)(tk.x != 0) << (i * 4 + 0);
    bits |= (unsigned)(tk.y != 0) << (i * 4 + 1);
    bits |= (unsigned)(tk.z != 0) << (i * 4 + 2);
    bits |= (unsigned)(tk.w != 0) << (i * 4 + 3);
  }

  // h[k] lives at float-offset (k>>4)*20 + (k&15)  (80 B chunk stride)
  __shared__ __align__(16) float h0s[2][160];
  __shared__ __align__(16) float h1s[2][160];
  if (tid < 160) {
    h0s[0][tid] = 0.0f;  // h0[-1]
    h1s[0][tid] = 0.0f;  // h1[-2]
  }

  const float* xp = xp0 + (size_t)b * TT * HH;
  float* outp = out + (size_t)b * TT * HH;

  float h0c0 = 0.f, h0c1 = 0.f, h0c2 = 0.f, h0c3 = 0.f;  // carried h0 (4 cols)
  float h1c0 = 0.f, h1c1 = 0.f, h1c2 = 0.f, h1c3 = 0.f;  // carried h1

  float4 xcur = *(const float4*)&xp[col];
  LDS_BARRIER();

  for (int t = 0; t < TT; ++t) {
    float4 xn = make_float4(0.f, 0.f, 0.f, 0.f);
    if (t + 1 < TT) xn = *(const float4*)&xp[(size_t)(t + 1) * HH + col];

    const int pr = t & 1;
    const int pw = pr ^ 1;
    const float* hb0 = h0s[pr];  // h0[t-1]
    const float* hb1 = h1s[pr];  // h1[t-2]

    f32x2 a0a = {0.f, 0.f}, a0b = {0.f, 0.f};
    f32x2 a1a = {0.f, 0.f}, a1b = {0.f, 0.f};

#define K1(HV0, HV1, idx)                                                     \
  a0a += (HV0)*w0a[idx];                                                      \
  a0b += (HV0)*w0b[idx];                                                      \
  a1a += (HV0)*wxa[idx];                                                      \
  a1b += (HV0)*wxb[idx];                                                      \
  a1a += (HV1)*wha[idx];                                                      \
  a1b += (HV1)*whb[idx];

#pragma unroll
    for (int c = 0; c < 4; ++c) {
      float4 hv0 = *(const float4*)&hb0[p * 20 + c * 4];
      float4 hv1 = *(const float4*)&hb1[p * 20 + c * 4];
      K1(hv0.x, hv1.x, c * 4 + 0)
      K1(hv0.y, hv1.y, c * 4 + 1)
      K1(hv0.z, hv1.z, c * 4 + 2)
      K1(hv0.w, hv1.w, c * 4 + 3)
    }
#undef K1

    float s00 = red8(a0a.x) + xcur.x;
    float s01 = red8(a0a.y) + xcur.y;
    float s02 = red8(a0b.x) + xcur.z;
    float s03 = red8(a0b.y) + xcur.w;
    float s10 = red8(a1a.x) + bias.x;
    float s11 = red8(a1a.y) + bias.y;
    float s12 = red8(a1b.x) + bias.z;
    float s13 = red8(a1b.y) + bias.w;

    // masks are block-uniform (depend on b,t only) -> cheap scalar branches
    unsigned wd0 = (unsigned)__builtin_amdgcn_readlane((int)bits, t >> 5);
    int m0 = (wd0 >> (t & 31)) & 1;
    if (m0) {
      h0c0 = tanh_fast(s00);
      h0c1 = tanh_fast(s01);
      h0c2 = tanh_fast(s02);
      h0c3 = tanh_fast(s03);
    }
    int m1 = 0;
    if (t > 0) {
      int t1 = t - 1;
      unsigned wd1 = (unsigned)__builtin_amdgcn_readlane((int)bits, t1 >> 5);
      m1 = (wd1 >> (t1 & 31)) & 1;
    }
    if (m1) {
      h1c0 = tanh_fast(s10);
      h1c1 = tanh_fast(s11);
      h1c2 = tanh_fast(s12);
      h1c3 = tanh_fast(s13);
    }

    if ((lane & 7) == 0) {
      const int widx = (jgg >> 2) * 20 + (jgg & 3) * 4;
      *(float4*)&h0s[pw][widx] = make_float4(h0c0, h0c1, h0c2, h0c3);
      *(float4*)&h1s[pw][widx] = make_float4(h1c0, h1c1, h1c2, h1c3);
      if (t > 0)
        *(float4*)&outp[(size_t)(t - 1) * HH + col] =
            make_float4(h1c0, h1c1, h1c2, h1c3);
    }
    LDS_BARRIER();
    xcur = xn;
  }

  // tail superstep (t == TT): h1[TT-1] from h0[TT-1] (h0s[0]) and h1[TT-2]
  // (h1s[0]); both written at t=TT-1 (pw=0), barrier passed.
  {
    const float* hb0 = h0s[0];
    const float* hb1 = h1s[0];
    f32x2 a1a = {0.f, 0.f}, a1b = {0.f, 0.f};

#define K1T(HV0, HV1, idx)                                                    \
  a1a += (HV0)*wxa[idx];                                                      \
  a1b += (HV0)*wxb[idx];                                                      \
  a1a += (HV1)*wha[idx];                                                      \
  a1b += (HV1)*whb[idx];

#pragma unroll
    for (int c = 0; c < 4; ++c) {
      float4 hv0 = *(const float4*)&hb0[p * 20 + c * 4];
      float4 hv1 = *(const float4*)&hb1[p * 20 + c * 4];
      K1T(hv0.x, hv1.x, c * 4 + 0)
      K1T(hv0.y, hv1.y, c * 4 + 1)
      K1T(hv0.z, hv1.z, c * 4 + 2)
      K1T(hv0.w, hv1.w, c * 4 + 3)
    }
#undef K1T

    float s10 = red8(a1a.x) + bias.x;
    float s11 = red8(a1a.y) + bias.y;
    float s12 = red8(a1b.x) + bias.z;
    float s13 = red8(a1b.y) + bias.w;

    const int t1 = TT - 1;
    unsigned wd1 = (unsigned)__builtin_amdgcn_readlane((int)bits, t1 >> 5);
    int m1 = (wd1 >> (t1 & 31)) & 1;
    if (m1) {
      h1c0 = tanh_fast(s10);
      h1c1 = tanh_fast(s11);
      h1c2 = tanh_fast(s12);
      h1c3 = tanh_fast(s13);
    }
    if ((lane & 7) == 0)
      *(float4*)&outp[(size_t)t1 * HH + col] =
          make_float4(h1c0, h1c1, h1c2, h1c3);
  }
}

extern "C" void kernel_launch(void* const* d_in, const int* in_sizes, int n_in,
                              void* d_out, int out_size, void* d_ws,
                              size_t ws_size, hipStream_t stream) {
  const int* tokens = (const int*)d_in[0];
  const float* emb = (const float*)d_in[1];
  const float* Wx0 = (const float*)d_in[2];
  const float* Wh0 = (const float*)d_in[3];
  const float* b0 = (const float*)d_in[4];
  const float* Wx1 = (const float*)d_in[5];
  const float* Wh1 = (const float*)d_in[6];
  const float* b1 = (const float*)d_in[7];
  float* out = (float*)d_out;
  float* ws = (float*)d_ws;  // 32 MB: xp0

  const int rows = BB * TT;           // 65536
  const int proj_blocks = rows / 64;  // 1024

  proj_kernel<true><<<proj_blocks, 256, 0, stream>>>(emb, tokens, Wx0, b0, ws);
  rnn_fused_kernel<<<BB, 256, 0, stream>>>(ws, out, Wh0, Wx1, Wh1, b1, tokens);
}

// Round 6
// 1226.550 us; speedup vs baseline: 12.1413x; 1.2692x over previous
//
#include <hip/hip_runtime.h>
#include <math.h>

#define BB 32
#define TT 2048
#define HH 128

typedef float f32x2 __attribute__((ext_vector_type(2)));

// LDS-only barrier: waits LDS ops (lgkmcnt), leaves global loads/stores in
// flight across the barrier.
#define LDS_BARRIER() asm volatile("s_waitcnt lgkmcnt(0)\n\ts_barrier" ::: "memory")

// DPP helper: any DPP ctrl (quad_perm 0x00-0xFF, row_ror 0x120+n, ...).
#define QPERM_F(v, CTRL)                                                      \
  __int_as_float(__builtin_amdgcn_update_dpp(                                 \
      0, __float_as_int(v), (CTRL), 0xF, 0xF, true))

// ds_swizzle pattern must be a literal constant at the builtin call site
// (R5 compile failure: runtime int arg rejected). Template makes it constexpr.
template <int OFFS>
__device__ __forceinline__ float swz_xor(float v) {
  return __int_as_float(__builtin_amdgcn_ds_swizzle(__float_as_int(v), OFFS));
}

// Merging butterfly stage: lanes with bit=0 end with x summed over the lane
// pair; lanes with bit=1 end with y summed. (2 cndmask + 1 perm + 1 add)
#define MERGE_DPP(x, y, bit, CTRL)                                            \
  ({                                                                          \
    float _k = (bit) ? (y) : (x);                                             \
    float _s = (bit) ? (x) : (y);                                             \
    _k + QPERM_F(_s, CTRL);                                                   \
  })
#define MERGE_SWZ(x, y, bit, OFFS)                                            \
  ({                                                                          \
    float _k = (bit) ? (y) : (x);                                             \
    float _s = (bit) ? (x) : (y);                                             \
    _k + swz_xor<OFFS>(_s);                                                   \
  })

__device__ __forceinline__ float tanh_fast(float s) {
  float ax = fabsf(s);
  float e = __expf(-2.0f * ax);
  float th = (1.0f - e) * __builtin_amdgcn_rcpf(1.0f + e);
  return copysignf(th, s);
}

// ---------------------------------------------------------------------------
// proj kernel: out[r, :] = emb[tokens[r]] @ Wx0 + b0   (layer-0 input proj)
// ---------------------------------------------------------------------------
template <bool GATHER>
__global__ __launch_bounds__(256) void proj_kernel(
    const float* __restrict__ src, const int* __restrict__ tokens,
    const float* __restrict__ W, const float* __restrict__ bias,
    float* __restrict__ out) {
  const int tid = threadIdx.x;
  const int jj = tid & 31;
  const int rr = tid >> 5;
  const int base = blockIdx.x * 64;

  __shared__ __align__(16) float srow[64][HH];
  __shared__ int stok[64];

  if (GATHER) {
    if (tid < 64) stok[tid] = tokens[base + tid];
    __syncthreads();
  }

#pragma unroll
  for (int i = 0; i < 8; ++i) {
    int idx = tid + i * 256;
    int row = idx >> 5;
    int c4 = idx & 31;
    const float* s = GATHER ? (src + (size_t)stok[row] * HH)
                            : (src + (size_t)(base + row) * HH);
    *(float4*)&srow[row][c4 * 4] = *(const float4*)&s[c4 * 4];
  }
  __syncthreads();

  float4 b4 = *(const float4*)&bias[jj * 4];
  float4 acc[8];
#pragma unroll
  for (int i = 0; i < 8; ++i) acc[i] = b4;

  for (int k = 0; k < HH; ++k) {
    float4 w4 = *(const float4*)&W[k * HH + jj * 4];
#pragma unroll
    for (int i = 0; i < 8; ++i) {
      float e = srow[rr * 8 + i][k];
      acc[i].x += e * w4.x;
      acc[i].y += e * w4.y;
      acc[i].z += e * w4.z;
      acc[i].w += e * w4.w;
    }
  }

#pragma unroll
  for (int i = 0; i < 8; ++i) {
    int row = base + rr * 8 + i;
    *(float4*)&out[(size_t)row * HH + jj * 4] = acc[i];
  }
}

// ---------------------------------------------------------------------------
// fused rnn kernel v6 (R6 = R5 with the ds_swizzle constexpr fix; R5 never
// compiled, theory untested).
//
// R4 post-mortem: v5 (256 thr, 192 weight floats/thread) needed ~230 live
// VGPRs; compiler allocated 132 and SANK ~100 weight loads into the 2048-step
// loop (L2-resident -> invisible in FETCH; visible as VALUBusy 52%/step-time
// 1714cy). Weights/thread = 49152/threads, so 512 threads -> 96 floats.
//
// Thread (jg = tid>>4 -> cols 4jg..4jg+3; p = lane&15 -> k in [8p,8p+8)):
//   - 48 f32x2 weight regs (Wh0/Wx1/Wh1), 48 pk_fma/step
//   - reads 8 h0 floats (shared by Wh0-dot AND Wx1-dot) + 8 h1 = 64 B
//   - distributed butterfly reduce over the 16 k-lanes: merge-select each
//     stage so lane ends with ONE output (col = 4jg+2b1+b0, layer = b2);
//     30 inst + 1 tanh vs naive 8 reduces + 8 tanh (96 inst)
//   - final xor8 stage via DPP row_ror:8 ((l+8)%16 == l^8), no swizzle
// h layout: 16-float chunk c at 20-float stride (proven v5): 16 half-chunk
// read addrs hit each bank value exactly twice -> 2-way = free (m136).
// ---------------------------------------------------------------------------
__global__ __launch_bounds__(512, 1) void rnn_fused_kernel(
    const float* __restrict__ xp0, float* __restrict__ out,
    const float* __restrict__ Wh0, const float* __restrict__ Wx1,
    const float* __restrict__ Wh1, const float* __restrict__ bias1,
    const int* __restrict__ tokens) {
  const int b = blockIdx.x;
  const int tid = threadIdx.x;
  const int lane = tid & 63;
  const int lb0 = lane & 1;
  const int lb1 = (lane >> 1) & 1;
  const int lb2 = (lane >> 2) & 1;  // layer select after reduce
  const int lb3 = (lane >> 3) & 1;  // duplicate half
  const int p = lane & 15;          // k-split 0..15, k in [8p, 8p+8)
  const int jg = tid >> 4;          // col-group 0..31
  const int colbase = jg * 4;
  const int kbase = p * 8;
  const int mycol = colbase + 2 * lb1 + lb0;  // output col after reduce

  // weights: rows kbase..kbase+7, cols colbase..colbase+3
  f32x2 w0a[8], w0b[8], wxa[8], wxb[8], wha[8], whb[8];
#pragma unroll
  for (int kk = 0; kk < 8; ++kk) {
    int row = kbase + kk;
    w0a[kk] = *(const f32x2*)&Wh0[row * HH + colbase];
    w0b[kk] = *(const f32x2*)&Wh0[row * HH + colbase + 2];
    wxa[kk] = *(const f32x2*)&Wx1[row * HH + colbase];
    wxb[kk] = *(const f32x2*)&Wx1[row * HH + colbase + 2];
    wha[kk] = *(const f32x2*)&Wh1[row * HH + colbase];
    whb[kk] = *(const f32x2*)&Wh1[row * HH + colbase + 2];
  }
  const float biasv = bias1[mycol];

  // mask bitmask: lane l holds bits for t in [32l, 32l+32); replicated/wave.
  const int* tok = tokens + b * TT;
  unsigned bits = 0;
#pragma unroll
  for (int i = 0; i < 8; ++i) {
    int4 tk = *(const int4*)&tok[lane * 32 + i * 4];
    bits |= (unsigned)(tk.x != 0) << (i * 4 + 0);
    bits |= (unsigned)(tk.y != 0) << (i * 4 + 1);
    bits |= (unsigned)(tk.z != 0) << (i * 4 + 2);
    bits |= (unsigned)(tk.w != 0) << (i * 4 + 3);
  }

  // h[k] at float-offset (k>>4)*20 + (k&15)  (80 B chunk stride)
  __shared__ __align__(16) float h0s[2][160];
  __shared__ __align__(16) float h1s[2][160];
  if (tid < 160) {
    h0s[0][tid] = 0.0f;  // h0[-1]
    h1s[0][tid] = 0.0f;  // h1[-2]
  }

  const float* xp = xp0 + (size_t)b * TT * HH + mycol;
  float* outp = out + (size_t)b * TT * HH + mycol;

  const int roff = (p >> 1) * 20 + (p & 1) * 8;        // my k-slice read offset
  const int wslot = (mycol >> 4) * 20 + (mycol & 15);  // my publish slot

  float h = 0.0f;  // carried state for my (layer, col)
  float xc = xp[0];
  float xn = xp[HH];
  LDS_BARRIER();

  for (int t = 0; t < TT; ++t) {
    const int pr = t & 1;
    const int pw = pr ^ 1;
    const float* hb0 = &h0s[pr][roff];
    const float* hb1 = &h1s[pr][roff];
    float4 hA0 = *(const float4*)&hb0[0];
    float4 hB0 = *(const float4*)&hb0[4];
    float4 hA1 = *(const float4*)&hb1[0];
    float4 hB1 = *(const float4*)&hb1[4];

    float x2 = 0.0f;
    if (t + 2 < TT) x2 = xp[(size_t)(t + 2) * HH];

    f32x2 a0a = {0.f, 0.f}, a0b = {0.f, 0.f};
    f32x2 a1a = {0.f, 0.f}, a1b = {0.f, 0.f};
#define KS(H0, H1, kk)                                                        \
  a0a += (H0)*w0a[kk];                                                        \
  a0b += (H0)*w0b[kk];                                                        \
  a1a += (H0)*wxa[kk];                                                        \
  a1b += (H0)*wxb[kk];                                                        \
  a1a += (H1)*wha[kk];                                                        \
  a1b += (H1)*whb[kk];
    KS(hA0.x, hA1.x, 0)
    KS(hA0.y, hA1.y, 1)
    KS(hA0.z, hA1.z, 2)
    KS(hA0.w, hA1.w, 3)
    KS(hB0.x, hB1.x, 4)
    KS(hB0.y, hB1.y, 5)
    KS(hB0.z, hB1.z, 6)
    KS(hB0.w, hB1.w, 7)
#undef KS

    // distributed reduce over 16 k-lanes; lane ends with (layer=lb2,
    // col = colbase + 2*lb1 + lb0), duplicated across lb3.
    float m0 = MERGE_DPP(a0a.x, a0a.y, lb0, 0xB1);  // L0 col parity
    float m1 = MERGE_DPP(a0b.x, a0b.y, lb0, 0xB1);
    float m2 = MERGE_DPP(a1a.x, a1a.y, lb0, 0xB1);  // L1 col parity
    float m3 = MERGE_DPP(a1b.x, a1b.y, lb0, 0xB1);
    float n0 = MERGE_DPP(m0, m1, lb1, 0x4E);   // L0 col pair
    float n1 = MERGE_DPP(m2, m3, lb1, 0x4E);   // L1 col pair
    float r = MERGE_SWZ(n0, n1, lb2, 0x101F);  // layer
    r += QPERM_F(r, 0x128);                    // xor8 == row_ror:8 in 16-group

    float s = r + (lb2 ? biasv : xc);

    // masks (block-uniform scalars; per-lane layer select)
    unsigned wd0 = (unsigned)__builtin_amdgcn_readlane((int)bits, t >> 5);
    int mk0 = (wd0 >> (t & 31)) & 1;
    int mk1 = 0;
    if (t > 0) {
      unsigned wd1 =
          (unsigned)__builtin_amdgcn_readlane((int)bits, (t - 1) >> 5);
      mk1 = (wd1 >> ((t - 1) & 31)) & 1;
    }
    int mm = lb2 ? mk1 : mk0;
    float th = tanh_fast(s);
    h = mm ? th : h;

    if (!lb3) {
      if (lb2) {
        h1s[pw][wslot] = h;  // publish h1[t-1]
        if (t > 0) outp[(size_t)(t - 1) * HH] = h;
      } else {
        h0s[pw][wslot] = h;  // publish h0[t]
      }
    }
    LDS_BARRIER();
    xc = xn;
    xn = x2;
  }

  // tail superstep (t == TT): h1[TT-1] from h0[TT-1] (h0s[0]) and h1[TT-2]
  // (h1s[0]); both written at t=TT-1 (pw=0), barrier passed.
  {
    const float* hb0 = &h0s[0][roff];
    const float* hb1 = &h1s[0][roff];
    float4 hA0 = *(const float4*)&hb0[0];
    float4 hB0 = *(const float4*)&hb0[4];
    float4 hA1 = *(const float4*)&hb1[0];
    float4 hB1 = *(const float4*)&hb1[4];

    f32x2 a1a = {0.f, 0.f}, a1b = {0.f, 0.f};
#define KT(H0, H1, kk)                                                        \
  a1a += (H0)*wxa[kk];                                                        \
  a1b += (H0)*wxb[kk];                                                        \
  a1a += (H1)*wha[kk];                                                        \
  a1b += (H1)*whb[kk];
    KT(hA0.x, hA1.x, 0)
    KT(hA0.y, hA1.y, 1)
    KT(hA0.z, hA1.z, 2)
    KT(hA0.w, hA1.w, 3)
    KT(hB0.x, hB1.x, 4)
    KT(hB0.y, hB1.y, 5)
    KT(hB0.z, hB1.z, 6)
    KT(hB0.w, hB1.w, 7)
#undef KT

    float m2 = MERGE_DPP(a1a.x, a1a.y, lb0, 0xB1);
    float m3 = MERGE_DPP(a1b.x, a1b.y, lb0, 0xB1);
    float n1 = MERGE_DPP(m2, m3, lb1, 0x4E);
    float r = n1 + swz_xor<0x101F>(n1);  // plain: only L1 values exist
    r += QPERM_F(r, 0x128);
    float s = r + biasv;

    const int t1 = TT - 1;
    unsigned wd1 = (unsigned)__builtin_amdgcn_readlane((int)bits, t1 >> 5);
    int mk1 = (wd1 >> (t1 & 31)) & 1;
    if (lb2) {  // lanes whose carried h is the h1 state
      float th = tanh_fast(s);
      float hv = mk1 ? th : h;
      if (!lb3) outp[(size_t)t1 * HH] = hv;
    }
  }
}

extern "C" void kernel_launch(void* const* d_in, const int* in_sizes, int n_in,
                              void* d_out, int out_size, void* d_ws,
                              size_t ws_size, hipStream_t stream) {
  const int* tokens = (const int*)d_in[0];
  const float* emb = (const float*)d_in[1];
  const float* Wx0 = (const float*)d_in[2];
  const float* Wh0 = (const float*)d_in[3];
  const float* b0 = (const float*)d_in[4];
  const float* Wx1 = (const float*)d_in[5];
  const float* Wh1 = (const float*)d_in[6];
  const float* b1 = (const float*)d_in[7];
  float* out = (float*)d_out;
  float* ws = (float*)d_ws;  // 32 MB: xp0

  const int rows = BB * TT;           // 65536
  const int proj_blocks = rows / 64;  // 1024

  proj_kernel<true><<<proj_blocks, 256, 0, stream>>>(emb, tokens, Wx0, b0, ws);
  rnn_fused_kernel<<<BB, 512, 0, stream>>>(ws, out, Wh0, Wx1, Wh1, b1, tokens);
}

// Round 7
// 1225.456 us; speedup vs baseline: 12.1521x; 1.0009x over previous
//
#include <hip/hip_runtime.h>
#include <math.h>

#define BB 32
#define TT 2048
#define HH 128

typedef float f32x2 __attribute__((ext_vector_type(2)));

// LDS-only barrier: waits LDS ops (lgkmcnt), leaves global loads/stores in
// flight across the barrier.
#define LDS_BARRIER() asm volatile("s_waitcnt lgkmcnt(0)\n\ts_barrier" ::: "memory")

// DPP helper: any DPP ctrl (quad_perm 0x00-0xFF, row_ror 0x120+n, ...).
#define QPERM_F(v, CTRL)                                                      \
  __int_as_float(__builtin_amdgcn_update_dpp(                                 \
      0, __float_as_int(v), (CTRL), 0xF, 0xF, true))

// ds_swizzle pattern must be a literal constant at the builtin call site.
template <int OFFS>
__device__ __forceinline__ float swz_xor(float v) {
  return __int_as_float(__builtin_amdgcn_ds_swizzle(__float_as_int(v), OFFS));
}

// Merging butterfly stage: lanes with bit=0 end with x summed over the lane
// pair; lanes with bit=1 end with y summed. (2 cndmask + 1 perm + 1 add)
#define MERGE_DPP(x, y, bit, CTRL)                                            \
  ({                                                                          \
    float _k = (bit) ? (y) : (x);                                             \
    float _s = (bit) ? (x) : (y);                                             \
    _k + QPERM_F(_s, CTRL);                                                   \
  })
#define MERGE_SWZ(x, y, bit, OFFS)                                            \
  ({                                                                          \
    float _k = (bit) ? (y) : (x);                                             \
    float _s = (bit) ? (x) : (y);                                             \
    _k + swz_xor<OFFS>(_s);                                                   \
  })

__device__ __forceinline__ float tanh_fast(float s) {
  float ax = fabsf(s);
  float e = __expf(-2.0f * ax);
  float th = (1.0f - e) * __builtin_amdgcn_rcpf(1.0f + e);
  return copysignf(th, s);
}

// ---------------------------------------------------------------------------
// proj kernel: out[r, :] = emb[tokens[r]] @ Wx0 + b0   (layer-0 input proj)
// ---------------------------------------------------------------------------
template <bool GATHER>
__global__ __launch_bounds__(256) void proj_kernel(
    const float* __restrict__ src, const int* __restrict__ tokens,
    const float* __restrict__ W, const float* __restrict__ bias,
    float* __restrict__ out) {
  const int tid = threadIdx.x;
  const int jj = tid & 31;
  const int rr = tid >> 5;
  const int base = blockIdx.x * 64;

  __shared__ __align__(16) float srow[64][HH];
  __shared__ int stok[64];

  if (GATHER) {
    if (tid < 64) stok[tid] = tokens[base + tid];
    __syncthreads();
  }

#pragma unroll
  for (int i = 0; i < 8; ++i) {
    int idx = tid + i * 256;
    int row = idx >> 5;
    int c4 = idx & 31;
    const float* s = GATHER ? (src + (size_t)stok[row] * HH)
                            : (src + (size_t)(base + row) * HH);
    *(float4*)&srow[row][c4 * 4] = *(const float4*)&s[c4 * 4];
  }
  __syncthreads();

  float4 b4 = *(const float4*)&bias[jj * 4];
  float4 acc[8];
#pragma unroll
  for (int i = 0; i < 8; ++i) acc[i] = b4;

  for (int k = 0; k < HH; ++k) {
    float4 w4 = *(const float4*)&W[k * HH + jj * 4];
#pragma unroll
    for (int i = 0; i < 8; ++i) {
      float e = srow[rr * 8 + i][k];
      acc[i].x += e * w4.x;
      acc[i].y += e * w4.y;
      acc[i].z += e * w4.z;
      acc[i].w += e * w4.w;
    }
  }

#pragma unroll
  for (int i = 0; i < 8; ++i) {
    int row = base + rr * 8 + i;
    *(float4*)&out[(size_t)row * HH + jj * 4] = acc[i];
  }
}

// ---------------------------------------------------------------------------
// fused rnn kernel v7 = v6 + amdgpu_waves_per_eu(2,2).
//
// R6 post-mortem: VGPR_Count=72 (<150 needed) -> RA sank the 96 weight
// floats/thread back into the 2048-step loop as L2 reloads (step 1320cy ~=
// 196KB/block/step / ~128B/cy L2). __launch_bounds__ 2nd arg only sets MIN
// waves/EU (an upper bound on VGPRs) — it never lowers the RA's occupancy
// target. amdgpu_waves_per_eu(2,2) fixes the MAX at 2 waves/EU (= the 1
// block/CU geometry gives anyway: 32 blocks / 256 CUs), telling the RA that
// occupancy>2 is worthless -> full 256-VGPR/wave budget -> weights stay
// resident. Tripwire: VGPR ~72 again => attribute ignored => asm-pin next.
//
// Structure (unchanged from v6): 512 thr, thread (jg=tid>>4 -> cols 4jg..+3;
// p=lane&15 -> k in [8p,8p+8)) holds 48 f32x2 weights (Wh0/Wx1/Wh1), reads
// 8 h0 + 8 h1 floats/step (64B, h0 shared by Wh0- AND Wx1-dots), 48 pk_fma,
// distributed merge-butterfly reduce (1 tanh/lane), publish via !lb3 lanes.
// ---------------------------------------------------------------------------
__global__ __launch_bounds__(512)
__attribute__((amdgpu_waves_per_eu(2, 2))) void rnn_fused_kernel(
    const float* __restrict__ xp0, float* __restrict__ out,
    const float* __restrict__ Wh0, const float* __restrict__ Wx1,
    const float* __restrict__ Wh1, const float* __restrict__ bias1,
    const int* __restrict__ tokens) {
  const int b = blockIdx.x;
  const int tid = threadIdx.x;
  const int lane = tid & 63;
  const int lb0 = lane & 1;
  const int lb1 = (lane >> 1) & 1;
  const int lb2 = (lane >> 2) & 1;  // layer select after reduce
  const int lb3 = (lane >> 3) & 1;  // duplicate half
  const int p = lane & 15;          // k-split 0..15, k in [8p, 8p+8)
  const int jg = tid >> 4;          // col-group 0..31
  const int colbase = jg * 4;
  const int kbase = p * 8;
  const int mycol = colbase + 2 * lb1 + lb0;  // output col after reduce

  // weights: rows kbase..kbase+7, cols colbase..colbase+3
  f32x2 w0a[8], w0b[8], wxa[8], wxb[8], wha[8], whb[8];
#pragma unroll
  for (int kk = 0; kk < 8; ++kk) {
    int row = kbase + kk;
    w0a[kk] = *(const f32x2*)&Wh0[row * HH + colbase];
    w0b[kk] = *(const f32x2*)&Wh0[row * HH + colbase + 2];
    wxa[kk] = *(const f32x2*)&Wx1[row * HH + colbase];
    wxb[kk] = *(const f32x2*)&Wx1[row * HH + colbase + 2];
    wha[kk] = *(const f32x2*)&Wh1[row * HH + colbase];
    whb[kk] = *(const f32x2*)&Wh1[row * HH + colbase + 2];
  }
  const float biasv = bias1[mycol];

  // mask bitmask: lane l holds bits for t in [32l, 32l+32); replicated/wave.
  const int* tok = tokens + b * TT;
  unsigned bits = 0;
#pragma unroll
  for (int i = 0; i < 8; ++i) {
    int4 tk = *(const int4*)&tok[lane * 32 + i * 4];
    bits |= (unsigned)(tk.x != 0) << (i * 4 + 0);
    bits |= (unsigned)(tk.y != 0) << (i * 4 + 1);
    bits |= (unsigned)(tk.z != 0) << (i * 4 + 2);
    bits |= (unsigned)(tk.w != 0) << (i * 4 + 3);
  }

  // h[k] at float-offset (k>>4)*20 + (k&15)  (80 B chunk stride)
  __shared__ __align__(16) float h0s[2][160];
  __shared__ __align__(16) float h1s[2][160];
  if (tid < 160) {
    h0s[0][tid] = 0.0f;  // h0[-1]
    h1s[0][tid] = 0.0f;  // h1[-2]
  }

  const float* xp = xp0 + (size_t)b * TT * HH + mycol;
  float* outp = out + (size_t)b * TT * HH + mycol;

  const int roff = (p >> 1) * 20 + (p & 1) * 8;        // my k-slice read offset
  const int wslot = (mycol >> 4) * 20 + (mycol & 15);  // my publish slot

  float h = 0.0f;  // carried state for my (layer, col)
  float xc = xp[0];
  float xn = xp[HH];
  LDS_BARRIER();

  for (int t = 0; t < TT; ++t) {
    const int pr = t & 1;
    const int pw = pr ^ 1;
    const float* hb0 = &h0s[pr][roff];
    const float* hb1 = &h1s[pr][roff];
    float4 hA0 = *(const float4*)&hb0[0];
    float4 hB0 = *(const float4*)&hb0[4];
    float4 hA1 = *(const float4*)&hb1[0];
    float4 hB1 = *(const float4*)&hb1[4];

    float x2 = 0.0f;
    if (t + 2 < TT) x2 = xp[(size_t)(t + 2) * HH];

    f32x2 a0a = {0.f, 0.f}, a0b = {0.f, 0.f};
    f32x2 a1a = {0.f, 0.f}, a1b = {0.f, 0.f};
#define KS(H0, H1, kk)                                                        \
  a0a += (H0)*w0a[kk];                                                        \
  a0b += (H0)*w0b[kk];                                                        \
  a1a += (H0)*wxa[kk];                                                        \
  a1b += (H0)*wxb[kk];                                                        \
  a1a += (H1)*wha[kk];                                                        \
  a1b += (H1)*whb[kk];
    KS(hA0.x, hA1.x, 0)
    KS(hA0.y, hA1.y, 1)
    KS(hA0.z, hA1.z, 2)
    KS(hA0.w, hA1.w, 3)
    KS(hB0.x, hB1.x, 4)
    KS(hB0.y, hB1.y, 5)
    KS(hB0.z, hB1.z, 6)
    KS(hB0.w, hB1.w, 7)
#undef KS

    // distributed reduce over 16 k-lanes; lane ends with (layer=lb2,
    // col = colbase + 2*lb1 + lb0), duplicated across lb3.
    float m0 = MERGE_DPP(a0a.x, a0a.y, lb0, 0xB1);  // L0 col parity
    float m1 = MERGE_DPP(a0b.x, a0b.y, lb0, 0xB1);
    float m2 = MERGE_DPP(a1a.x, a1a.y, lb0, 0xB1);  // L1 col parity
    float m3 = MERGE_DPP(a1b.x, a1b.y, lb0, 0xB1);
    float n0 = MERGE_DPP(m0, m1, lb1, 0x4E);   // L0 col pair
    float n1 = MERGE_DPP(m2, m3, lb1, 0x4E);   // L1 col pair
    float r = MERGE_SWZ(n0, n1, lb2, 0x101F);  // layer
    r += QPERM_F(r, 0x128);                    // xor8 == row_ror:8 in 16-group

    float s = r + (lb2 ? biasv : xc);

    // masks (block-uniform scalars; per-lane layer select)
    unsigned wd0 = (unsigned)__builtin_amdgcn_readlane((int)bits, t >> 5);
    int mk0 = (wd0 >> (t & 31)) & 1;
    int mk1 = 0;
    if (t > 0) {
      unsigned wd1 =
          (unsigned)__builtin_amdgcn_readlane((int)bits, (t - 1) >> 5);
      mk1 = (wd1 >> ((t - 1) & 31)) & 1;
    }
    int mm = lb2 ? mk1 : mk0;
    float th = tanh_fast(s);
    h = mm ? th : h;

    if (!lb3) {
      if (lb2) {
        h1s[pw][wslot] = h;  // publish h1[t-1]
        if (t > 0) outp[(size_t)(t - 1) * HH] = h;
      } else {
        h0s[pw][wslot] = h;  // publish h0[t]
      }
    }
    LDS_BARRIER();
    xc = xn;
    xn = x2;
  }

  // tail superstep (t == TT): h1[TT-1] from h0[TT-1] (h0s[0]) and h1[TT-2]
  // (h1s[0]); both written at t=TT-1 (pw=0), barrier passed.
  {
    const float* hb0 = &h0s[0][roff];
    const float* hb1 = &h1s[0][roff];
    float4 hA0 = *(const float4*)&hb0[0];
    float4 hB0 = *(const float4*)&hb0[4];
    float4 hA1 = *(const float4*)&hb1[0];
    float4 hB1 = *(const float4*)&hb1[4];

    f32x2 a1a = {0.f, 0.f}, a1b = {0.f, 0.f};
#define KT(H0, H1, kk)                                                        \
  a1a += (H0)*wxa[kk];                                                        \
  a1b += (H0)*wxb[kk];                                                        \
  a1a += (H1)*wha[kk];                                                        \
  a1b += (H1)*whb[kk];
    KT(hA0.x, hA1.x, 0)
    KT(hA0.y, hA1.y, 1)
    KT(hA0.z, hA1.z, 2)
    KT(hA0.w, hA1.w, 3)
    KT(hB0.x, hB1.x, 4)
    KT(hB0.y, hB1.y, 5)
    KT(hB0.z, hB1.z, 6)
    KT(hB0.w, hB1.w, 7)
#undef KT

    float m2 = MERGE_DPP(a1a.x, a1a.y, lb0, 0xB1);
    float m3 = MERGE_DPP(a1b.x, a1b.y, lb0, 0xB1);
    float n1 = MERGE_DPP(m2, m3, lb1, 0x4E);
    float r = n1 + swz_xor<0x101F>(n1);  // plain: only L1 values exist
    r += QPERM_F(r, 0x128);
    float s = r + biasv;

    const int t1 = TT - 1;
    unsigned wd1 = (unsigned)__builtin_amdgcn_readlane((int)bits, t1 >> 5);
    int mk1 = (wd1 >> (t1 & 31)) & 1;
    if (lb2) {  // lanes whose carried h is the h1 state
      float th = tanh_fast(s);
      float hv = mk1 ? th : h;
      if (!lb3) outp[(size_t)t1 * HH] = hv;
    }
  }
}

extern "C" void kernel_launch(void* const* d_in, const int* in_sizes, int n_in,
                              void* d_out, int out_size, void* d_ws,
                              size_t ws_size, hipStream_t stream) {
  const int* tokens = (const int*)d_in[0];
  const float* emb = (const float*)d_in[1];
  const float* Wx0 = (const float*)d_in[2];
  const float* Wh0 = (const float*)d_in[3];
  const float* b0 = (const float*)d_in[4];
  const float* Wx1 = (const float*)d_in[5];
  const float* Wh1 = (const float*)d_in[6];
  const float* b1 = (const float*)d_in[7];
  float* out = (float*)d_out;
  float* ws = (float*)d_ws;  // 32 MB: xp0

  const int rows = BB * TT;           // 65536
  const int proj_blocks = rows / 64;  // 1024

  proj_kernel<true><<<proj_blocks, 256, 0, stream>>>(emb, tokens, Wx0, b0, ws);
  rnn_fused_kernel<<<BB, 512, 0, stream>>>(ws, out, Wh0, Wx1, Wh1, b1, tokens);
}

// Round 8
// 1212.069 us; speedup vs baseline: 12.2863x; 1.0110x over previous
//
#include <hip/hip_runtime.h>
#include <math.h>

#define BB 32
#define TT 2048
#define HH 128

typedef float f32x2 __attribute__((ext_vector_type(2)));

// LDS-only barrier: waits LDS ops (lgkmcnt), leaves global loads/stores in
// flight across the barrier.
#define LDS_BARRIER() asm volatile("s_waitcnt lgkmcnt(0)\n\ts_barrier" ::: "memory")

// DPP helper: any DPP ctrl (quad_perm 0x00-0xFF, row_ror 0x120+n, ...).
#define QPERM_F(v, CTRL)                                                      \
  __int_as_float(__builtin_amdgcn_update_dpp(                                 \
      0, __float_as_int(v), (CTRL), 0xF, 0xF, true))

// ds_swizzle pattern must be a literal constant at the builtin call site.
template <int OFFS>
__device__ __forceinline__ float swz_xor(float v) {
  return __int_as_float(__builtin_amdgcn_ds_swizzle(__float_as_int(v), OFFS));
}

// Merging butterfly stage: lanes with bit=0 end with x summed over the lane
// pair; lanes with bit=1 end with y summed. (2 cndmask + 1 perm + 1 add)
#define MERGE_DPP(x, y, bit, CTRL)                                            \
  ({                                                                          \
    float _k = (bit) ? (y) : (x);                                             \
    float _s = (bit) ? (x) : (y);                                             \
    _k + QPERM_F(_s, CTRL);                                                   \
  })
#define MERGE_SWZ(x, y, bit, OFFS)                                            \
  ({                                                                          \
    float _k = (bit) ? (y) : (x);                                             \
    float _s = (bit) ? (x) : (y);                                             \
    _k + swz_xor<OFFS>(_s);                                                   \
  })

__device__ __forceinline__ float tanh_fast(float s) {
  float ax = fabsf(s);
  float e = __expf(-2.0f * ax);
  float th = (1.0f - e) * __builtin_amdgcn_rcpf(1.0f + e);
  return copysignf(th, s);
}

// ---------------------------------------------------------------------------
// proj kernel: out[r, :] = emb[tokens[r]] @ Wx0 + b0   (layer-0 input proj)
// ---------------------------------------------------------------------------
template <bool GATHER>
__global__ __launch_bounds__(256) void proj_kernel(
    const float* __restrict__ src, const int* __restrict__ tokens,
    const float* __restrict__ W, const float* __restrict__ bias,
    float* __restrict__ out) {
  const int tid = threadIdx.x;
  const int jj = tid & 31;
  const int rr = tid >> 5;
  const int base = blockIdx.x * 64;

  __shared__ __align__(16) float srow[64][HH];
  __shared__ int stok[64];

  if (GATHER) {
    if (tid < 64) stok[tid] = tokens[base + tid];
    __syncthreads();
  }

#pragma unroll
  for (int i = 0; i < 8; ++i) {
    int idx = tid + i * 256;
    int row = idx >> 5;
    int c4 = idx & 31;
    const float* s = GATHER ? (src + (size_t)stok[row] * HH)
                            : (src + (size_t)(base + row) * HH);
    *(float4*)&srow[row][c4 * 4] = *(const float4*)&s[c4 * 4];
  }
  __syncthreads();

  float4 b4 = *(const float4*)&bias[jj * 4];
  float4 acc[8];
#pragma unroll
  for (int i = 0; i < 8; ++i) acc[i] = b4;

  for (int k = 0; k < HH; ++k) {
    float4 w4 = *(const float4*)&W[k * HH + jj * 4];
#pragma unroll
    for (int i = 0; i < 8; ++i) {
      float e = srow[rr * 8 + i][k];
      acc[i].x += e * w4.x;
      acc[i].y += e * w4.y;
      acc[i].z += e * w4.z;
      acc[i].w += e * w4.w;
    }
  }

#pragma unroll
  for (int i = 0; i < 8; ++i) {
    int row = base + rr * 8 + i;
    *(float4*)&out[(size_t)row * HH + jj * 4] = acc[i];
  }
}

// ---------------------------------------------------------------------------
// fused rnn kernel v8 = v7 + inline-asm weight pinning.
//
// R7 post-mortem: waves_per_eu(2,2) raised the VGPR CAP (72->88 used) but the
// scheduler still REMATERIALIZES most of the 96 weight floats inside the
// 2048-step loop (time unchanged 1126us; VALUBusy ~63% of active-CU time ~=
// 830cy/step vs ~400cy for the intended ~100-inst step — the extra is reload
// address math + vmcnt waits; L2-resident reloads are invisible in FETCH).
// Fix: empty asm volatile("" : "+v"(w)) after the loads makes each weight an
// opaque register value — not re-derivable from the load — forcing it live in
// a VGPR across the loop. Budget 256/wave at 2 waves/EU; need ~150.
// Tripwire: VGPR_Count <= 110 => pinning failed/spilled => restructure.
//
// Structure (unchanged from v6): 512 thr, thread (jg=tid>>4 -> cols 4jg..+3;
// p=lane&15 -> k in [8p,8p+8)) holds 48 f32x2 weights (Wh0/Wx1/Wh1), reads
// 8 h0 + 8 h1 floats/step (64B, h0 shared by Wh0- AND Wx1-dots), 48 pk_fma,
// distributed merge-butterfly reduce (1 tanh/lane), publish via !lb3 lanes.
// Bank conflicts 8.39M/dispatch = the 2-way h-read aliasing = ~128cy/step,
// free-ish per m136 — deliberately not touched this round.
// ---------------------------------------------------------------------------
__global__ __launch_bounds__(512)
__attribute__((amdgpu_waves_per_eu(2, 2))) void rnn_fused_kernel(
    const float* __restrict__ xp0, float* __restrict__ out,
    const float* __restrict__ Wh0, const float* __restrict__ Wx1,
    const float* __restrict__ Wh1, const float* __restrict__ bias1,
    const int* __restrict__ tokens) {
  const int b = blockIdx.x;
  const int tid = threadIdx.x;
  const int lane = tid & 63;
  const int lb0 = lane & 1;
  const int lb1 = (lane >> 1) & 1;
  const int lb2 = (lane >> 2) & 1;  // layer select after reduce
  const int lb3 = (lane >> 3) & 1;  // duplicate half
  const int p = lane & 15;          // k-split 0..15, k in [8p, 8p+8)
  const int jg = tid >> 4;          // col-group 0..31
  const int colbase = jg * 4;
  const int kbase = p * 8;
  const int mycol = colbase + 2 * lb1 + lb0;  // output col after reduce

  // weights: rows kbase..kbase+7, cols colbase..colbase+3
  f32x2 w0a[8], w0b[8], wxa[8], wxb[8], wha[8], whb[8];
#pragma unroll
  for (int kk = 0; kk < 8; ++kk) {
    int row = kbase + kk;
    w0a[kk] = *(const f32x2*)&Wh0[row * HH + colbase];
    w0b[kk] = *(const f32x2*)&Wh0[row * HH + colbase + 2];
    wxa[kk] = *(const f32x2*)&Wx1[row * HH + colbase];
    wxb[kk] = *(const f32x2*)&Wx1[row * HH + colbase + 2];
    wha[kk] = *(const f32x2*)&Wh1[row * HH + colbase];
    whb[kk] = *(const f32x2*)&Wh1[row * HH + colbase + 2];
  }

  // Pin the weights: after this, each value is asm-redefined -> the compiler
  // cannot rematerialize the load inside the loop; must stay register-live.
#define PIN4(a, b, c, d) asm volatile("" : "+v"(a), "+v"(b), "+v"(c), "+v"(d))
#pragma unroll
  for (int q = 0; q < 8; q += 4) {
    PIN4(w0a[q], w0a[q + 1], w0a[q + 2], w0a[q + 3]);
    PIN4(w0b[q], w0b[q + 1], w0b[q + 2], w0b[q + 3]);
    PIN4(wxa[q], wxa[q + 1], wxa[q + 2], wxa[q + 3]);
    PIN4(wxb[q], wxb[q + 1], wxb[q + 2], wxb[q + 3]);
    PIN4(wha[q], wha[q + 1], wha[q + 2], wha[q + 3]);
    PIN4(whb[q], whb[q + 1], whb[q + 2], whb[q + 3]);
  }
#undef PIN4

  const float biasv = bias1[mycol];

  // mask bitmask: lane l holds bits for t in [32l, 32l+32); replicated/wave.
  const int* tok = tokens + b * TT;
  unsigned bits = 0;
#pragma unroll
  for (int i = 0; i < 8; ++i) {
    int4 tk = *(const int4*)&tok[lane * 32 + i * 4];
    bits |= (unsigned)(tk.x != 0) << (i * 4 + 0);
    bits |= (unsigned)(tk.y != 0) << (i * 4 + 1);
    bits |= (unsigned)(tk.z != 0) << (i * 4 + 2);
    bits |= (unsigned)(tk.w != 0) << (i * 4 + 3);
  }

  // h[k] at float-offset (k>>4)*20 + (k&15)  (80 B chunk stride)
  __shared__ __align__(16) float h0s[2][160];
  __shared__ __align__(16) float h1s[2][160];
  if (tid < 160) {
    h0s[0][tid] = 0.0f;  // h0[-1]
    h1s[0][tid] = 0.0f;  // h1[-2]
  }

  const float* xp = xp0 + (size_t)b * TT * HH + mycol;
  float* outp = out + (size_t)b * TT * HH + mycol;

  const int roff = (p >> 1) * 20 + (p & 1) * 8;        // my k-slice read offset
  const int wslot = (mycol >> 4) * 20 + (mycol & 15);  // my publish slot

  float h = 0.0f;  // carried state for my (layer, col)
  float xc = xp[0];
  float xn = xp[HH];
  LDS_BARRIER();

  for (int t = 0; t < TT; ++t) {
    const int pr = t & 1;
    const int pw = pr ^ 1;
    const float* hb0 = &h0s[pr][roff];
    const float* hb1 = &h1s[pr][roff];
    float4 hA0 = *(const float4*)&hb0[0];
    float4 hB0 = *(const float4*)&hb0[4];
    float4 hA1 = *(const float4*)&hb1[0];
    float4 hB1 = *(const float4*)&hb1[4];

    float x2 = 0.0f;
    if (t + 2 < TT) x2 = xp[(size_t)(t + 2) * HH];

    f32x2 a0a = {0.f, 0.f}, a0b = {0.f, 0.f};
    f32x2 a1a = {0.f, 0.f}, a1b = {0.f, 0.f};
#define KS(H0, H1, kk)                                                        \
  a0a += (H0)*w0a[kk];                                                        \
  a0b += (H0)*w0b[kk];                                                        \
  a1a += (H0)*wxa[kk];                                                        \
  a1b += (H0)*wxb[kk];                                                        \
  a1a += (H1)*wha[kk];                                                        \
  a1b += (H1)*whb[kk];
    KS(hA0.x, hA1.x, 0)
    KS(hA0.y, hA1.y, 1)
    KS(hA0.z, hA1.z, 2)
    KS(hA0.w, hA1.w, 3)
    KS(hB0.x, hB1.x, 4)
    KS(hB0.y, hB1.y, 5)
    KS(hB0.z, hB1.z, 6)
    KS(hB0.w, hB1.w, 7)
#undef KS

    // distributed reduce over 16 k-lanes; lane ends with (layer=lb2,
    // col = colbase + 2*lb1 + lb0), duplicated across lb3.
    float m0 = MERGE_DPP(a0a.x, a0a.y, lb0, 0xB1);  // L0 col parity
    float m1 = MERGE_DPP(a0b.x, a0b.y, lb0, 0xB1);
    float m2 = MERGE_DPP(a1a.x, a1a.y, lb0, 0xB1);  // L1 col parity
    float m3 = MERGE_DPP(a1b.x, a1b.y, lb0, 0xB1);
    float n0 = MERGE_DPP(m0, m1, lb1, 0x4E);   // L0 col pair
    float n1 = MERGE_DPP(m2, m3, lb1, 0x4E);   // L1 col pair
    float r = MERGE_SWZ(n0, n1, lb2, 0x101F);  // layer
    r += QPERM_F(r, 0x128);                    // xor8 == row_ror:8 in 16-group

    float s = r + (lb2 ? biasv : xc);

    // masks (block-uniform scalars; per-lane layer select)
    unsigned wd0 = (unsigned)__builtin_amdgcn_readlane((int)bits, t >> 5);
    int mk0 = (wd0 >> (t & 31)) & 1;
    int mk1 = 0;
    if (t > 0) {
      unsigned wd1 =
          (unsigned)__builtin_amdgcn_readlane((int)bits, (t - 1) >> 5);
      mk1 = (wd1 >> ((t - 1) & 31)) & 1;
    }
    int mm = lb2 ? mk1 : mk0;
    float th = tanh_fast(s);
    h = mm ? th : h;

    if (!lb3) {
      if (lb2) {
        h1s[pw][wslot] = h;  // publish h1[t-1]
        if (t > 0) outp[(size_t)(t - 1) * HH] = h;
      } else {
        h0s[pw][wslot] = h;  // publish h0[t]
      }
    }
    LDS_BARRIER();
    xc = xn;
    xn = x2;
  }

  // tail superstep (t == TT): h1[TT-1] from h0[TT-1] (h0s[0]) and h1[TT-2]
  // (h1s[0]); both written at t=TT-1 (pw=0), barrier passed.
  {
    const float* hb0 = &h0s[0][roff];
    const float* hb1 = &h1s[0][roff];
    float4 hA0 = *(const float4*)&hb0[0];
    float4 hB0 = *(const float4*)&hb0[4];
    float4 hA1 = *(const float4*)&hb1[0];
    float4 hB1 = *(const float4*)&hb1[4];

    f32x2 a1a = {0.f, 0.f}, a1b = {0.f, 0.f};
#define KT(H0, H1, kk)                                                        \
  a1a += (H0)*wxa[kk];                                                        \
  a1b += (H0)*wxb[kk];                                                        \
  a1a += (H1)*wha[kk];                                                        \
  a1b += (H1)*whb[kk];
    KT(hA0.x, hA1.x, 0)
    KT(hA0.y, hA1.y, 1)
    KT(hA0.z, hA1.z, 2)
    KT(hA0.w, hA1.w, 3)
    KT(hB0.x, hB1.x, 4)
    KT(hB0.y, hB1.y, 5)
    KT(hB0.z, hB1.z, 6)
    KT(hB0.w, hB1.w, 7)
#undef KT

    float m2 = MERGE_DPP(a1a.x, a1a.y, lb0, 0xB1);
    float m3 = MERGE_DPP(a1b.x, a1b.y, lb0, 0xB1);
    float n1 = MERGE_DPP(m2, m3, lb1, 0x4E);
    float r = n1 + swz_xor<0x101F>(n1);  // plain: only L1 values exist
    r += QPERM_F(r, 0x128);
    float s = r + biasv;

    const int t1 = TT - 1;
    unsigned wd1 = (unsigned)__builtin_amdgcn_readlane((int)bits, t1 >> 5);
    int mk1 = (wd1 >> (t1 & 31)) & 1;
    if (lb2) {  // lanes whose carried h is the h1 state
      float th = tanh_fast(s);
      float hv = mk1 ? th : h;
      if (!lb3) outp[(size_t)t1 * HH] = hv;
    }
  }
}

extern "C" void kernel_launch(void* const* d_in, const int* in_sizes, int n_in,
                              void* d_out, int out_size, void* d_ws,
                              size_t ws_size, hipStream_t stream) {
  const int* tokens = (const int*)d_in[0];
  const float* emb = (const float*)d_in[1];
  const float* Wx0 = (const float*)d_in[2];
  const float* Wh0 = (const float*)d_in[3];
  const float* b0 = (const float*)d_in[4];
  const float* Wx1 = (const float*)d_in[5];
  const float* Wh1 = (const float*)d_in[6];
  const float* b1 = (const float*)d_in[7];
  float* out = (float*)d_out;
  float* ws = (float*)d_ws;  // 32 MB: xp0

  const int rows = BB * TT;           // 65536
  const int proj_blocks = rows / 64;  // 1024

  proj_kernel<true><<<proj_blocks, 256, 0, stream>>>(emb, tokens, Wx0, b0, ws);
  rnn_fused_kernel<<<BB, 512, 0, stream>>>(ws, out, Wh0, Wx1, Wh1, b1, tokens);
}